// Round 7
// baseline (151.033 us; speedup 1.0000x reference)
//
#include <hip/hip_runtime.h>
#include <hip/hip_bf16.h>

#define TPB 512
#define PREP_TPB 256

constexpr int B_    = 262144;
constexpr int WIN_  = 5;
constexpr int VOCAB_= 100000;
constexpr int EMB_  = 50;
constexpr int HID_  = 250;
constexpr int OUT_  = 36;
constexpr int KP    = 256;   // padded K for layer 2 (HID 250 -> 256)
constexpr int NP    = 256;   // padded hidden
constexpr int OP    = 48;    // padded out cols (3 x 16)
constexpr int BM    = 64;    // rows per block
constexpr int K1    = 320;   // layer-1 K: 5 windows x 64 (each 50 padded to 64)
constexpr int ROWB  = 640;   // xs row bytes = K1 * 2

typedef __attribute__((ext_vector_type(8))) short fragA;  // 8 bf16
typedef __attribute__((ext_vector_type(4))) float fragC;  // 4 f32 acc

__device__ __forceinline__ short f2b(float f) {
    __hip_bfloat16 h = __float2bfloat16(f);      // native RNE cvt
    return *reinterpret_cast<short*>(&h);
}

__device__ __forceinline__ unsigned pack2(float x, float y) {
    return (unsigned)(unsigned short)f2b(x) | ((unsigned)(unsigned short)f2b(y) << 16);
}

__device__ __forceinline__ float fast_tanh(float x) {
    float e = __expf(2.f * x);
    return 1.f - __fdividef(2.f, e + 1.f);
}

// xs tile: 64 rows x 640B. Row stride 640 % 128 == 0 -> all rows alias the same
// bank cycle; XOR-swizzle byte ^ ((row&7)<<4) spreads 8 consecutive rows across
// the 128B bank cycle -> conflict-free fragA reads / b128 writes (R5: 0 conflicts).
__device__ __forceinline__ void* xp(char* xs, int row, int b) {
    return xs + row * ROWB + (b ^ ((row & 7) << 4));
}

// emb_table f32 [VOCAB][50] -> bf16 [VOCAB][64], cols 50..63 zero (row = 128B aligned)
__global__ void prep_emb(const float* __restrict__ emb, short* __restrict__ emb_b) {
    int id = blockIdx.x * PREP_TPB + threadIdx.x;      // one dword (2 cols) each
    if (id >= VOCAB_ * 32) return;
    int row = id >> 5, c2 = id & 31;
    unsigned v = 0u;
    if (c2 < 25) {
        float2 f = *(const float2*)(emb + row * EMB_ + 2 * c2);  // 8B-aligned
        v = pack2(f.x, f.y);
    }
    ((unsigned*)emb_b)[id] = v;
}

// W1 -> wT[n][k1] bf16 (256x320 window-padded), W2 -> woT[o][k] (48x256),
// b_in -> f32[256] zero-padded, b_out -> f32[48] zero-padded
__global__ void prep_weights(const float* __restrict__ w_in,
                             const float* __restrict__ w_out,
                             const float* __restrict__ b_in,
                             const float* __restrict__ b_out,
                             short* __restrict__ wT,
                             short* __restrict__ woT,
                             float* __restrict__ b_in_p,
                             float* __restrict__ b_out_p) {
    int id = blockIdx.x * PREP_TPB + threadIdx.x;
    if (id < NP * K1) {
        int n = id / K1, kp = id - n * K1;
        int w = kp >> 6, e = kp & 63;                  // window, elem-in-window
        float v = (n < HID_ && e < EMB_) ? w_in[(w * EMB_ + e) * HID_ + n] : 0.f;
        wT[id] = f2b(v);
        return;
    }
    int id2 = id - NP * K1;
    if (id2 < OP * KP) {
        int o = id2 >> 8, k = id2 & 255;
        float v = (o < OUT_ && k < HID_) ? w_out[k * OUT_ + o] : 0.f;
        woT[id2] = f2b(v);
        return;
    }
    int id3 = id2 - OP * KP;
    if (id3 < NP) { b_in_p[id3] = (id3 < HID_) ? b_in[id3] : 0.f; return; }
    int id4 = id3 - NP;
    if (id4 < OP) { b_out_p[id4] = (id4 < OUT_) ? b_out[id4] : 0.f; }
}

template<bool BF>
__launch_bounds__(TPB, 8)
__global__ void tagger_main(const int* __restrict__ idx,
                            const float* __restrict__ emb,
                            const short* __restrict__ emb_b,
                            const float* __restrict__ b_in_p,
                            const float* __restrict__ b_out_p,
                            const short* __restrict__ wT,
                            const short* __restrict__ woT,
                            float* __restrict__ out) {
    __shared__ char xs[BM * ROWB];     // 40960 B -> 4 blocks/CU (x 512 thr = 100% occ)

    const int tid   = threadIdx.x;
    const int lane  = tid & 63;
    const int wave  = tid >> 6;        // 0..7
    const int l16   = lane & 15;
    const int khalf = lane >> 4;
    const int r0    = blockIdx.x * BM;

    // ---- gather into xs [64][5*128B] ----
    if constexpr (BF) {
        #pragma unroll
        for (int it = 0; it < 5; ++it) {
            int c   = it * TPB + tid;          // chunk 0..2559
            int p   = c >> 3, sub = c & 7;     // (row,win) pair, 16B chunk
            int row = p / 5, win = p - row * 5;
            int iv  = idx[r0 * WIN_ + p];
            fragA v = {0, 0, 0, 0, 0, 0, 0, 0};
            if (iv >= 0 && iv < VOCAB_)
                v = *(const fragA*)(emb_b + iv * 64 + sub * 8);   // 16B aligned
            *(fragA*)xp(xs, row, win * 128 + sub * 16) = v;
        }
    } else {
        const int sub = tid & 3;
        #pragma unroll
        for (int it = 0; it < 3; ++it) {
            int p = it * 128 + (tid >> 2);
            if (p < BM * WIN_) {
                int row = p / 5, win = p - row * 5;
                int iv  = idx[r0 * WIN_ + p];
                bool valid = (iv >= 0 && iv < VOCAB_);
                const float* base = emb + (valid ? iv : 0) * EMB_;
                #pragma unroll
                for (int j = 0; j < 7; ++j) {
                    int ch = sub + 4 * j;
                    if (ch < 25) {
                        float2 v = make_float2(0.f, 0.f);
                        if (valid) v = *(const float2*)(base + 2 * ch);
                        *(unsigned*)xp(xs, row, win * 128 + 4 * ch) = pack2(v.x, v.y);
                    }
                }
                for (int ch = 25 + sub; ch < 32; ch += 4)   // zero pad cols 50..63
                    *(unsigned*)xp(xs, row, win * 128 + 4 * ch) = 0u;
            }
        }
    }
    __syncthreads();

    // ---- layer 1: swapped operands -> D[n][batch]; wave owns 64 rows x 32 n-cols.
    fragC acc[4][2];
    #pragma unroll
    for (int mf = 0; mf < 4; ++mf)
        #pragma unroll
        for (int nf = 0; nf < 2; ++nf)
            acc[mf][nf] = (fragC){0.f, 0.f, 0.f, 0.f};

    const int nb    = wave * 32;
    const int bbase = (nb + l16) * K1 + khalf * 8;   // wT frag base (lane row = n)

    #pragma unroll 2
    for (int kk = 0; kk < 10; ++kk) {
        fragA a[4], b[2];
        #pragma unroll
        for (int mf = 0; mf < 4; ++mf)
            a[mf] = *(const fragA*)xp(xs, mf * 16 + l16, kk * 64 + khalf * 16);
        #pragma unroll
        for (int nf = 0; nf < 2; ++nf)
            b[nf] = *(const fragA*)&wT[bbase + nf * 16 * K1 + kk * 32];
        #pragma unroll
        for (int mf = 0; mf < 4; ++mf)
            #pragma unroll
            for (int nf = 0; nf < 2; ++nf)
                acc[mf][nf] = __builtin_amdgcn_mfma_f32_16x16x32_bf16(b[nf], a[mf], acc[mf][nf], 0, 0, 0);
    }

    __syncthreads();  // all xs (x) reads complete before overwriting with h

    // ---- epilogue 1: thread owns batch row (mf*16+l16), 4 consecutive n ----
    #pragma unroll
    for (int nf = 0; nf < 2; ++nf) {
        const int n0 = nb + nf * 16 + khalf * 4;
        const float4 bi = *(const float4*)&b_in_p[n0];
        #pragma unroll
        for (int mf = 0; mf < 4; ++mf) {
            const int row = mf * 16 + l16;
            uint2 v;
            v.x = pack2(fast_tanh(acc[mf][nf][0] + bi.x), fast_tanh(acc[mf][nf][1] + bi.y));
            v.y = pack2(fast_tanh(acc[mf][nf][2] + bi.z), fast_tanh(acc[mf][nf][3] + bi.w));
            *(uint2*)xp(xs, row, 2 * n0) = v;   // 8B write, swizzle keeps 8B align
        }
    }
    __syncthreads();

    // ---- layer 2: 12 tiles (4 row-groups x 3 col-groups) over 8 waves ----
    for (int t = wave; t < 12; t += 8) {
        const int rf = t & 3, of = t >> 2;
        fragC acc2 = (fragC){0.f, 0.f, 0.f, 0.f};
        #pragma unroll 2
        for (int kk = 0; kk < 8; ++kk) {
            fragA ha = *(const fragA*)xp(xs, rf * 16 + l16, 64 * kk + 16 * khalf);
            fragA wb = *(const fragA*)&woT[(of * 16 + l16) * KP + kk * 32 + khalf * 8];
            acc2 = __builtin_amdgcn_mfma_f32_16x16x32_bf16(wb, ha, acc2, 0, 0, 0);
        }
        const int o0 = of * 16 + khalf * 4;
        if (o0 < OUT_) {
            const int row = r0 + rf * 16 + l16;
            const float4 bo = *(const float4*)&b_out_p[o0];
            float4 v;
            v.x = acc2[0] + bo.x;
            v.y = acc2[1] + bo.y;
            v.z = acc2[2] + bo.z;
            v.w = acc2[3] + bo.w;
            *(float4*)&out[row * OUT_ + o0] = v;   // 16B aligned: 144*row + 4*o0
        }
    }
}

extern "C" void kernel_launch(void* const* d_in, const int* in_sizes, int n_in,
                              void* d_out, int out_size, void* d_ws, size_t ws_size,
                              hipStream_t stream) {
    const int*   idx   = (const int*)d_in[0];
    const float* emb   = (const float*)d_in[1];
    const float* w_in  = (const float*)d_in[2];
    const float* b_in  = (const float*)d_in[3];
    const float* w_out = (const float*)d_in[4];
    const float* b_out = (const float*)d_in[5];
    float* out = (float*)d_out;

    const size_t emb_b_elems = (size_t)VOCAB_ * 64;                 // 12.8 MB
    const size_t tail_elems  = (size_t)NP * K1 + OP * KP + 2 * (NP + OP);
    const size_t need_bf = (emb_b_elems + tail_elems + 256) * 2;
    const bool bf = (ws_size >= need_bf);

    short* emb_b = nullptr;
    short* wT;
    if (bf) {
        emb_b = (short*)d_ws;
        wT    = emb_b + emb_b_elems;
        prep_emb<<<VOCAB_ * 32 / PREP_TPB, PREP_TPB, 0, stream>>>(emb, emb_b);
    } else {
        wT = (short*)d_ws;
    }
    short* woT = wT + NP * K1;
    float* b_in_p  = (float*)(woT + OP * KP);
    float* b_out_p = b_in_p + NP;

    int prep_threads = NP * K1 + OP * KP + NP + OP;
    prep_weights<<<(prep_threads + PREP_TPB - 1) / PREP_TPB, PREP_TPB, 0, stream>>>(
        w_in, w_out, b_in, b_out, wT, woT, b_in_p, b_out_p);

    if (bf)
        tagger_main<true><<<B_ / BM, TPB, 0, stream>>>(idx, emb, emb_b, b_in_p, b_out_p, wT, woT, out);
    else
        tagger_main<false><<<B_ / BM, TPB, 0, stream>>>(idx, emb, emb_b, b_in_p, b_out_p, wT, woT, out);
}